// Round 9
// baseline (118.060 us; speedup 1.0000x reference)
//
#include <hip/hip_runtime.h>
#include <hip/hip_bf16.h>

#define NQ 12
typedef __hip_bfloat16 bf16;

__device__ __forceinline__ float b2f(unsigned int u) {
  union { unsigned int i; float f; } v; v.i = u << 16; return v.f;
}

// Dtype-adaptive scalar load (world: f32 inputs — HW-proven R5/R6/R7).
__device__ __forceinline__ float ldv(const void* p, int i, bool f32) {
  if (f32) return ((const float*)p)[i];
  return b2f((unsigned int)((const unsigned short*)p)[i]);
}

// Composite permutation of the 12 sequential ring CNOTs. HW-proven (R2/R7).
__device__ __forceinline__ constexpr int ringperm(int d) {
  int a = d ^ ((d & 1) << 11);
  return a ^ (a >> 1);
}

// fp16 pack/unpack (round-nearest; 4 round-trips -> ~1e-3 rel amp error)
__device__ __forceinline__ unsigned int pk2(float a, float b) {
  union { _Float16 h; unsigned short u; } ca, cb;
  ca.h = (_Float16)a; cb.h = (_Float16)b;
  return (unsigned int)ca.u | ((unsigned int)cb.u << 16);
}
__device__ __forceinline__ float up16(unsigned int w, int sh) {
  union { unsigned short u; _Float16 h; } c;
  c.u = (unsigned short)(w >> sh);
  return (float)c.h;
}

// One wave per batch element; 64 fp32 amps/lane in registers; 8KB LDS of
// packed fp16 for the two transpose passes per layer.
// Layout A: amp[j] = state[(j<<6)|lane]  (qubits 0..5 <-> j bits 5..0)
// Layout B: amp[j] = state[(lane<<6)|j]  (qubits 6..11 <-> j bits 5..0)
// Pass 1 (A->B, folds ring-CNOT perm): word W1(u') holds states (u', u'^0x800),
//   W1(v) = v ^ ((v>>5)&31) over v = state&0x7FF. Pass 2 (B->A): word W2(v'),
//   v' = (state[6:11]<<5)|state[0:4], pairs by state bit5, W2(v)=v^((v>>5)&31).
// All four lane->bank maps verified injective per 32-lane phase (the R8
// conflict post-mortem model): conflict-free.
__global__ __launch_bounds__(64) void qsim_kernel(
    const void* __restrict__ x,    // [B,12]
    const void* __restrict__ w,    // [2,12]
    const void* __restrict__ Wm,   // [2,12]
    const void* __restrict__ bv,   // [2]
    void* __restrict__ out)        // [B,2]
{
  __shared__ unsigned int st2[2048];   // 8192 B
  const int lane = threadIdx.x;
  const int b = blockIdx.x;

  // ---- inline dtype probe (HW-proven R5/R6/R7) ----
  bool f32;
  {
    const unsigned short* xu = (const unsigned short*)x;
    int insane = 0;
#pragma unroll
    for (int i = 0; i < 16; ++i) {
      float v = b2f((unsigned int)xu[2 * i]);
      float a = fabsf(v);
      if (!(a <= 64.f) || (a != 0.f && a < 1e-8f)) ++insane;
    }
    f32 = (insane >= 2);
  }

  // ---- init product state, layout A (R7-verbatim) ----
  float lp = 1.f;
#pragma unroll
  for (int q = 6; q < 12; ++q) {
    float h = 0.5f * ldv(x, b * NQ + q, f32);
    lp *= ((lane >> (11 - q)) & 1) ? __sinf(h) : __cosf(h);
  }
  float amp[64];
  {
    float h0 = 0.5f * ldv(x, b * NQ + 0, f32);
    amp[0] = lp * __cosf(h0);
    amp[1] = lp * __sinf(h0);
#pragma unroll
    for (int lvl = 1; lvl < 6; ++lvl) {
      float h = 0.5f * ldv(x, b * NQ + lvl, f32);
      float cc = __cosf(h), ss = __sinf(h);
#pragma unroll
      for (int i = (1 << lvl) - 1; i >= 0; --i) {
        float t = amp[i];
        amp[2 * i]     = t * cc;
        amp[2 * i + 1] = t * ss;
      }
    }
  }

  // ---- per-thread address bases ----
  const int tw1 = lane ^ (lane >> 5);                 // pass-1 write
  const int rbf = ringperm(lane << 6);                // pass-1 read base (full)
  const int sb0 = rbf & 0x7FF;
  const int RB  = sb0 ^ ((sb0 >> 5) & 31);            // pass-1 read, swizzled
  const int sh0 = ((rbf >> 11) & 1) << 4;             // pass-1 half-shift, even j
  const int sh1 = sh0 ^ 16;                           //                  odd j
  const int tw2 = (lane << 5) ^ (lane & 31);          // pass-2 write
  const int lm  = lane & 31;                          // pass-2 read
  const int sh2 = ((lane >> 5) & 1) << 4;             // pass-2 half-shift

#pragma unroll 1
  for (int l = 0; l < 2; ++l) {
    // ---- Pass 1: ring-CNOT perm + transpose, A -> B (fp16-packed) ----
    __syncthreads();
#pragma unroll
    for (int j = 0; j < 32; ++j) {
      const int cj = (j << 6) ^ ((j << 1) & 31);      // compile-time
      st2[cj ^ tw1] = pk2(amp[j], amp[j | 32]);       // (bit11=0, bit11=1)
    }
    __syncthreads();
#pragma unroll
    for (int j = 0; j < 64; ++j) {
      const int sj  = ringperm(j);                    // compile-time
      const int sjm = sj & 0x7FF;
      const int SW  = sjm ^ ((sjm >> 5) & 31);        // compile-time
      amp[j] = up16(st2[RB ^ SW], (j & 1) ? sh1 : sh0);  // half = s11 = rb11^j0
    }

    // ---- RY gates, qubits 6..11 (register pairs in layout B; R7-verbatim) ----
#pragma unroll
    for (int q = 6; q < 12; ++q) {
      float h = 0.5f * ldv(w, l * NQ + q, f32);
      const float c = __cosf(h), s = __sinf(h);
      const int m = 1 << (11 - q);
#pragma unroll
      for (int j = 0; j < 64; ++j) {
        if (j & m) continue;
        float v0 = amp[j], v1 = amp[j | m];
        amp[j]     = fmaf(c, v0, -s * v1);
        amp[j | m] = fmaf(s, v0,  c * v1);
      }
    }

    // ---- Pass 2: pure transpose, B -> A (fp16-packed) ----
    __syncthreads();
#pragma unroll
    for (int j = 0; j < 32; ++j)
      st2[tw2 ^ j] = pk2(amp[j], amp[j | 32]);        // (bit5=0, bit5=1)
    __syncthreads();
#pragma unroll
    for (int j = 0; j < 64; ++j) {
      const int cj = (j << 5) ^ (j & 31);             // compile-time
      amp[j] = up16(st2[cj ^ lm], sh2);               // half = lane bit5
    }

    // ---- RY gates, qubits 0..5 (register pairs in layout A; R7-verbatim) ----
#pragma unroll
    for (int q = 0; q < 6; ++q) {
      float h = 0.5f * ldv(w, l * NQ + q, f32);
      const float c = __cosf(h), s = __sinf(h);
      const int m = 1 << (5 - q);
#pragma unroll
      for (int j = 0; j < 64; ++j) {
        if (j & m) continue;
        float v0 = amp[j], v1 = amp[j | m];
        amp[j]     = fmaf(c, v0, -s * v1);
        amp[j | m] = fmaf(s, v0,  c * v1);
      }
    }
  }

  // ---- measurement in layout A (R7-verbatim) ----
  float P = 0.f, z0 = 0.f, z1 = 0.f, z2 = 0.f, z3 = 0.f, z4 = 0.f, z5 = 0.f;
#pragma unroll
  for (int j = 0; j < 64; ++j) {
    float pr = amp[j] * amp[j];
    P  += pr;
    z0 += (j & 32) ? -pr : pr;
    z1 += (j & 16) ? -pr : pr;
    z2 += (j & 8)  ? -pr : pr;
    z3 += (j & 4)  ? -pr : pr;
    z4 += (j & 2)  ? -pr : pr;
    z5 += (j & 1)  ? -pr : pr;
  }

  // ---- fused linear head (R7-verbatim) ----
  float t0, t1;
#pragma unroll
  for (int r = 0; r < 2; ++r) {
    float acc = z0 * ldv(Wm, r * NQ + 0, f32) + z1 * ldv(Wm, r * NQ + 1, f32)
              + z2 * ldv(Wm, r * NQ + 2, f32) + z3 * ldv(Wm, r * NQ + 3, f32)
              + z4 * ldv(Wm, r * NQ + 4, f32) + z5 * ldv(Wm, r * NQ + 5, f32);
    float wsum = 0.f;
#pragma unroll
    for (int q = 6; q < 12; ++q) {
      float wv = ldv(Wm, r * NQ + q, f32);
      wsum += ((lane >> (11 - q)) & 1) ? -wv : wv;
    }
    acc = fmaf(P, wsum, acc);
    if (r == 0) t0 = acc; else t1 = acc;
  }
#pragma unroll
  for (int off = 32; off; off >>= 1) {
    t0 += __shfl_xor(t0, off, 64);
    t1 += __shfl_xor(t1, off, 64);
  }
  if (lane < 2) {
    float o = ((lane == 0) ? t0 : t1) + ldv(bv, lane, f32);
    if (f32) ((float*)out)[b * 2 + lane] = o;
    else     ((bf16*)out)[b * 2 + lane] = __float2bfloat16(o);
  }
}

extern "C" void kernel_launch(void* const* d_in, const int* in_sizes, int n_in,
                              void* d_out, int out_size, void* d_ws, size_t ws_size,
                              hipStream_t stream) {
  const void* x  = d_in[0];
  const void* w  = d_in[1];
  const void* Wm = d_in[2];
  const void* bv = d_in[3];
  const int batch = out_size / 2;   // out is [B, 2]
  qsim_kernel<<<dim3(batch), dim3(64), 0, stream>>>(x, w, Wm, bv, d_out);
}

// Round 11
// 95.725 us; speedup vs baseline: 1.2333x; 1.2333x over previous
//
#include <hip/hip_runtime.h>
#include <hip/hip_bf16.h>

#define NQ 12
typedef __hip_bfloat16 bf16;

__device__ __forceinline__ float b2f(unsigned int u) {
  union { unsigned int i; float f; } v; v.i = u << 16; return v.f;
}

// Dtype-adaptive scalar load (world: f32 — probe-verified on HW in R5/R6/R7).
__device__ __forceinline__ float ldv(const void* p, int i, bool f32) {
  if (f32) return ((const float*)p)[i];
  return b2f((unsigned int)((const unsigned short*)p)[i]);
}

// Composite permutation of the 12 sequential ring CNOTs (i,(i+1)%12).
// Qubit q <-> bit (11-q). new_state[d] = old_state[ringperm(d)].
// HW-verified (R2, R7 passes).
__device__ __forceinline__ int ringperm(int d) {
  int a = d ^ ((d & 1) << 11);
  return a ^ (a >> 1);
}

// LDS bank swizzle (GF(2)-linear involution): transpose reads become <=2-way
// (free, m136) instead of 32-way. HW-verified: SQ_LDS_BANK_CONFLICT = 0 (R7).
__device__ __forceinline__ int swz(int p) { return p ^ ((p >> 6) & 31); }

// One wave per batch element; 64 amps/lane.
// Layout A: amp[j] = state[(j<<6)|lane]; Layout B: amp[j] = state[(lane<<6)|j].
// Per layer: LDS pass (CNOT perm + transpose A->B), register RY q6..11,
// LDS pass (transpose B->A), register RY q0..5. RYs commute -> exact.
// This is the Round-7 kernel VERBATIM (passed: 43.5us dispatch, absmax 9.8e-4).
__global__ __launch_bounds__(64) void qsim_kernel(
    const void* __restrict__ x,    // [B,12] f32
    const void* __restrict__ w,    // [2,12] f32
    const void* __restrict__ Wm,   // [2,12] f32
    const void* __restrict__ bv,   // [2]    f32
    void* __restrict__ out)        // [B,2]  f32
{
  __shared__ float st[4096];
  const int lane = threadIdx.x;
  const int b = blockIdx.x;

  // ---- inline dtype probe: low halves of random f32 are ~87% insane as
  // bf16; genuine bf16 data is sane. Robust (P(err) ~ 5e-13).
  bool f32;
  {
    const unsigned short* xu = (const unsigned short*)x;
    int insane = 0;
#pragma unroll
    for (int i = 0; i < 16; ++i) {
      float v = b2f((unsigned int)xu[2 * i]);
      float a = fabsf(v);
      if (!(a <= 64.f) || (a != 0.f && a < 1e-8f)) ++insane;  // NaN fails a<=64
    }
    f32 = (insane >= 2);
  }

  // ---- init product state, layout A ----
  float lp = 1.f;
#pragma unroll
  for (int q = 6; q < 12; ++q) {
    float h = 0.5f * ldv(x, b * NQ + q, f32);
    lp *= ((lane >> (11 - q)) & 1) ? __sinf(h) : __cosf(h);
  }
  float amp[64];
  {
    float h0 = 0.5f * ldv(x, b * NQ + 0, f32);
    amp[0] = lp * __cosf(h0);
    amp[1] = lp * __sinf(h0);
#pragma unroll
    for (int lvl = 1; lvl < 6; ++lvl) {
      float h = 0.5f * ldv(x, b * NQ + lvl, f32);
      float cc = __cosf(h), ss = __sinf(h);
#pragma unroll
      for (int i = (1 << lvl) - 1; i >= 0; --i) {
        float t = amp[i];
        amp[2 * i]     = t * cc;
        amp[2 * i + 1] = t * ss;
      }
    }
  }

#pragma unroll 1
  for (int l = 0; l < 2; ++l) {
    // ---- Pass 1: ring-CNOT perm + transpose, A -> B ----
    __syncthreads();
#pragma unroll
    for (int j = 0; j < 64; ++j) st[((j << 6) ^ (j & 31)) ^ lane] = amp[j];
    __syncthreads();
    {
      const int rb = swz(ringperm(lane << 6));
#pragma unroll
      for (int j = 0; j < 64; ++j) amp[j] = st[rb ^ swz(ringperm(j))];
    }

    // ---- RY gates, qubits 6..11 (register pairs in layout B) ----
#pragma unroll
    for (int q = 6; q < 12; ++q) {
      float h = 0.5f * ldv(w, l * NQ + q, f32);
      const float c = __cosf(h), s = __sinf(h);
      const int m = 1 << (11 - q);
#pragma unroll
      for (int j = 0; j < 64; ++j) {
        if (j & m) continue;
        float v0 = amp[j], v1 = amp[j | m];
        amp[j]     = fmaf(c, v0, -s * v1);
        amp[j | m] = fmaf(s, v0,  c * v1);
      }
    }

    // ---- Pass 2: pure transpose, B -> A ----
    __syncthreads();
    {
      const int wb = (lane << 6) ^ (lane & 31);
#pragma unroll
      for (int j = 0; j < 64; ++j) st[wb ^ j] = amp[j];
    }
    __syncthreads();
#pragma unroll
    for (int j = 0; j < 64; ++j) amp[j] = st[((j << 6) ^ (j & 31)) ^ lane];

    // ---- RY gates, qubits 0..5 (register pairs in layout A) ----
#pragma unroll
    for (int q = 0; q < 6; ++q) {
      float h = 0.5f * ldv(w, l * NQ + q, f32);
      const float c = __cosf(h), s = __sinf(h);
      const int m = 1 << (5 - q);
#pragma unroll
      for (int j = 0; j < 64; ++j) {
        if (j & m) continue;
        float v0 = amp[j], v1 = amp[j | m];
        amp[j]     = fmaf(c, v0, -s * v1);
        amp[j | m] = fmaf(s, v0,  c * v1);
      }
    }
  }

  // ---- measurement in layout A ----
  float P = 0.f, z0 = 0.f, z1 = 0.f, z2 = 0.f, z3 = 0.f, z4 = 0.f, z5 = 0.f;
#pragma unroll
  for (int j = 0; j < 64; ++j) {
    float pr = amp[j] * amp[j];
    P  += pr;
    z0 += (j & 32) ? -pr : pr;
    z1 += (j & 16) ? -pr : pr;
    z2 += (j & 8)  ? -pr : pr;
    z3 += (j & 4)  ? -pr : pr;
    z4 += (j & 2)  ? -pr : pr;
    z5 += (j & 1)  ? -pr : pr;
  }

  // ---- fused linear head: per-lane partials, then 2 butterflies ----
  float t0, t1;
#pragma unroll
  for (int r = 0; r < 2; ++r) {
    float acc = z0 * ldv(Wm, r * NQ + 0, f32) + z1 * ldv(Wm, r * NQ + 1, f32)
              + z2 * ldv(Wm, r * NQ + 2, f32) + z3 * ldv(Wm, r * NQ + 3, f32)
              + z4 * ldv(Wm, r * NQ + 4, f32) + z5 * ldv(Wm, r * NQ + 5, f32);
    float wsum = 0.f;
#pragma unroll
    for (int q = 6; q < 12; ++q) {
      float wv = ldv(Wm, r * NQ + q, f32);
      wsum += ((lane >> (11 - q)) & 1) ? -wv : wv;
    }
    acc = fmaf(P, wsum, acc);
    if (r == 0) t0 = acc; else t1 = acc;
  }
#pragma unroll
  for (int off = 32; off; off >>= 1) {
    t0 += __shfl_xor(t0, off, 64);
    t1 += __shfl_xor(t1, off, 64);
  }
  if (lane < 2) {
    float o = ((lane == 0) ? t0 : t1) + ldv(bv, lane, f32);
    if (f32) ((float*)out)[b * 2 + lane] = o;
    else     ((bf16*)out)[b * 2 + lane] = __float2bfloat16(o);
  }
}

extern "C" void kernel_launch(void* const* d_in, const int* in_sizes, int n_in,
                              void* d_out, int out_size, void* d_ws, size_t ws_size,
                              hipStream_t stream) {
  const void* x  = d_in[0];
  const void* w  = d_in[1];
  const void* Wm = d_in[2];
  const void* bv = d_in[3];
  const int batch = out_size / 2;   // out is [B, 2]
  qsim_kernel<<<dim3(batch), dim3(64), 0, stream>>>(x, w, Wm, bv, d_out);
}